// Round 1
// baseline (107.890 us; speedup 1.0000x reference)
//
#include <hip/hip_runtime.h>
#include <hip/hip_bf16.h>

#define NFFT 1024
#define HOP 256
#define NB 16
#define NF 513
#define NT 1024
#define KP 1088                    // padded K: 17*64
#define MM (NB*NT)                 // 16384
#define LOUT ((NT-1)*HOP + NFFT)   // 262912

typedef __bf16 bf16x8 __attribute__((ext_vector_type(8)));
typedef float f32x4 __attribute__((ext_vector_type(4)));

__device__ __forceinline__ void gload_lds16(const void* g, void* l) {
  __builtin_amdgcn_global_load_lds(
      (const __attribute__((address_space(1))) void*)g,
      (__attribute__((address_space(3))) void*)l, 16, 0, 0);
}

// kerT[n][c] = scale(c) * (c<513 ? cos : -sin)(2*pi*f*n/1024) * win[n] / 1024 * coeff
// coeff = HOP / sum(win^2) = 256/384. Zeros for c >= 1026 (K padding).
__global__ void build_kerT(__hip_bfloat16* __restrict__ kerT) {
  int idx = blockIdx.x * 256 + threadIdx.x;   // grid sized exactly
  int n = idx / KP;
  int c = idx - n * KP;
  float v = 0.f;
  if (c < 1026) {
    int f = (c < 513) ? c : c - 513;
    int ph = (f * n) & (NFFT - 1);            // exact mod-1024 phase
    const float w0 = 6.283185307179586f / NFFT;
    float s, co;
    __sincosf((float)ph * w0, &s, &co);
    float wn = 0.5f - 0.5f * __cosf((float)n * w0);
    float sc = (c < 513) ? ((c == 0 || c == 512) ? 1.f : 2.f) : 2.f;
    float base = sc * wn * (1.0f / NFFT) * (256.0f / 384.0f);
    v = (c < 513) ? co * base : -s * base;
  }
  kerT[idx] = __float2bfloat16(v);
}

// A[b*1024+t][c] bf16, c<513: x[b][c][t][0]; 513<=c<1026: x[b][c-513][t][1]; pad zeros.
// LDS transpose: read coalesced along t (float2 = both ri), write coalesced along c.
__global__ void pack_a(const float* __restrict__ x, __hip_bfloat16* __restrict__ A) {
  __shared__ float2 tile[64][65];
  int b = blockIdx.z, f0 = blockIdx.y * 64, t0 = blockIdx.x * 64;
  int tid = threadIdx.x;
  int tl = tid & 63, th = tid >> 6;
#pragma unroll
  for (int r = 0; r < 16; ++r) {
    int fl = r * 4 + th;
    int f = f0 + fl;
    float2 v = make_float2(0.f, 0.f);
    if (f < NF)
      v = *(const float2*)(x + (((size_t)b * NF + f) * NT + (t0 + tl)) * 2);
    tile[fl][tl] = v;
  }
  __syncthreads();
#pragma unroll
  for (int r = 0; r < 16; ++r) {
    int tloc = r * 4 + th;
    size_t row = (size_t)(b * NT + t0 + tloc) * KP;
    int cf = f0 + tl;
    float2 v = tile[tl][tloc];
    if (cf < 513) A[row + cf] = __float2bfloat16(v.x);
    int c2 = 513 + cf;
    if (c2 < KP) A[row + c2] = __float2bfloat16(v.y);   // also zero-fills pad 1026..1087
  }
}

// C[m][n] = sum_c A[m][c] * kerT[n][c]; 128x128 tile, BK=64, 4 waves, 4x4 16x16x32 frags.
__global__ __launch_bounds__(256) void gemm_frames(
    const __hip_bfloat16* __restrict__ A, const __hip_bfloat16* __restrict__ Bt,
    float* __restrict__ frames, float* __restrict__ out, int use_atomic) {
  __shared__ __align__(16) __hip_bfloat16 sA[128 * 64];
  __shared__ __align__(16) __hip_bfloat16 sB[128 * 64];
  int tid = threadIdx.x;
  int lane = tid & 63;
  int wv = tid >> 6;
  int wmo = (wv >> 1) * 64;
  int wno = (wv & 1) * 64;
  int M0 = blockIdx.x * 128;
  int N0 = blockIdx.y * 128;

  f32x4 acc[4][4] = {};
  const int kl = (tid & 7) * 8;

  for (int kt = 0; kt < KP / 64; ++kt) {
    if (kt) __syncthreads();
    int k0 = kt * 64;
#pragma unroll
    for (int seg = 0; seg < 4; ++seg) {
      int ml = seg * 32 + (tid >> 3);
      gload_lds16(A + (size_t)(M0 + ml) * KP + k0 + kl, &sA[ml * 64 + kl]);
      gload_lds16(Bt + (size_t)(N0 + ml) * KP + k0 + kl, &sB[ml * 64 + kl]);
    }
    __syncthreads();
#pragma unroll
    for (int ks = 0; ks < 2; ++ks) {
      bf16x8 af[4], bfr[4];
      int krow = ks * 32 + (lane >> 4) * 8;
#pragma unroll
      for (int mi = 0; mi < 4; ++mi)
        af[mi] = *(const bf16x8*)&sA[(wmo + mi * 16 + (lane & 15)) * 64 + krow];
#pragma unroll
      for (int ni = 0; ni < 4; ++ni)
        bfr[ni] = *(const bf16x8*)&sB[(wno + ni * 16 + (lane & 15)) * 64 + krow];
#pragma unroll
      for (int mi = 0; mi < 4; ++mi)
#pragma unroll
        for (int ni = 0; ni < 4; ++ni)
          acc[mi][ni] = __builtin_amdgcn_mfma_f32_16x16x32_bf16(
              af[mi], bfr[ni], acc[mi][ni], 0, 0, 0);
    }
  }

  int bb = M0 >> 10;
  int tb = M0 & 1023;
  if (!use_atomic) {
#pragma unroll
    for (int mi = 0; mi < 4; ++mi) {
      int mrow = wmo + mi * 16 + (lane >> 4) * 4;
#pragma unroll
      for (int ni = 0; ni < 4; ++ni) {
        int ncol = N0 + wno + ni * 16 + (lane & 15);
#pragma unroll
        for (int r = 0; r < 4; ++r)
          frames[(size_t)(M0 + mrow + r) * NFFT + ncol] = acc[mi][ni][r];
      }
    }
  } else {
#pragma unroll
    for (int mi = 0; mi < 4; ++mi) {
#pragma unroll
      for (int ni = 0; ni < 4; ++ni) {
        int ncol = N0 + wno + ni * 16 + (lane & 15);
#pragma unroll
        for (int r = 0; r < 4; ++r) {
          int t = tb + wmo + mi * 16 + (lane >> 4) * 4 + r;
          atomicAdd(&out[(size_t)bb * LOUT + (size_t)t * HOP + ncol], acc[mi][ni][r]);
        }
      }
    }
  }
}

// out[b][l] = sum over t with 0 <= l - 256t < 1024 of frames[b][t][l-256t]
__global__ void ola(const float* __restrict__ frames, float* __restrict__ out, int total) {
  int idx = blockIdx.x * blockDim.x + threadIdx.x;
  int stride = gridDim.x * blockDim.x;
  for (; idx < total; idx += stride) {
    int b = idx / LOUT;
    int l = idx - b * LOUT;
    int thi = l >> 8; if (thi > NT - 1) thi = NT - 1;
    int tlo = (l - (NFFT - HOP)) >> 8; if (tlo < 0) tlo = 0;  // ceil((l-1023)/256)
    float s = 0.f;
    for (int t = tlo; t <= thi; ++t)
      s += frames[((size_t)b * NT + t) * NFFT + (l - t * HOP)];
    out[idx] = s;
  }
}

extern "C" void kernel_launch(void* const* d_in, const int* in_sizes, int n_in,
                              void* d_out, int out_size, void* d_ws, size_t ws_size,
                              hipStream_t stream) {
  (void)in_sizes; (void)n_in;
  const float* x = (const float*)d_in[0];
  float* out = (float*)d_out;
  char* ws = (char*)d_ws;
  __hip_bfloat16* A = (__hip_bfloat16*)ws;
  __hip_bfloat16* kerT = (__hip_bfloat16*)(ws + (size_t)MM * KP * 2);
  size_t base = (size_t)MM * KP * 2 + (size_t)NFFT * KP * 2;
  float* frames = (float*)(ws + base);
  int use_atomic = (ws_size < base + (size_t)MM * NFFT * 4) ? 1 : 0;

  build_kerT<<<dim3(NFFT * KP / 256), dim3(256), 0, stream>>>(kerT);
  pack_a<<<dim3(16, 9, 16), dim3(256), 0, stream>>>(x, A);
  if (use_atomic)
    hipMemsetAsync(d_out, 0, (size_t)out_size * sizeof(float), stream);
  gemm_frames<<<dim3(MM / 128, NFFT / 128), dim3(256), 0, stream>>>(A, kerT, frames, out, use_atomic);
  if (!use_atomic)
    ola<<<dim3(2048), dim3(256), 0, stream>>>(frames, out, NB * LOUT);
}